// Round 2
// baseline (208.190 us; speedup 1.0000x reference)
//
#include <hip/hip_runtime.h>
#include <hip/hip_bf16.h>
#include <math.h>

#define LEAKY 0.01f
#define B_    2048
#define F_    512
#define H_    64
#define K_    8
#define D_    128
#define ASR_  128
#define MM_   768
#define OUT_  256
#define PROJ_IN 66432          // 128+768+512*128
#define ZK    4992             // 896 + 512*8 (reduced K after folding emb into proj_w)
#define PK    4096             // F_*K_  (P columns)

// ---------------- workspace layout (bytes) ----------------
// P  : [B_][PK]   bf16  @ 0            16,777,216
// Wn : [OUT_][ZK] bf16  @ 16,777,216    2,555,904
// total 19,333,120  (round-1 was 50.2 MB -> OOB past ws_size corrupted
// pristine inputs; this build must stay small)

typedef unsigned short u16;
typedef u16   u16x4 __attribute__((ext_vector_type(4)));
typedef u16   u16x8 __attribute__((ext_vector_type(8)));
typedef short s16x8 __attribute__((ext_vector_type(8)));   // MFMA bf16 A/B frag
typedef float f32x4 __attribute__((ext_vector_type(4)));   // MFMA acc

__device__ __forceinline__ u16 f2bf(float x) {   // RNE float->bf16 bits
  unsigned int u = __float_as_uint(x);
  u += 0x7fffu + ((u >> 16) & 1u);
  return (u16)(u >> 16);
}

// ---------------------------------------------------------------------------
// Per-feature tiny MLP -> softmax probs -> P (bf16). Block = (f, b-chunk).
__global__ __launch_bounds__(256) void probs_kernel(
    const float* __restrict__ stat, const float* __restrict__ w1,
    const float* __restrict__ b1v, const float* __restrict__ w2,
    const float* __restrict__ b2v, const float* __restrict__ tauv,
    u16* __restrict__ P) {
  const int f = blockIdx.x;
  const int b = blockIdx.y * 256 + threadIdx.x;
  __shared__ float s_w1s[H_], s_b1[H_], s_w2[H_ * K_], s_b2[K_], s_tau[K_];
  const int t = threadIdx.x;
  if (t < H_) {
    const float* wf = w1 + f * 3 * H_;
    s_w1s[t] = wf[t] + wf[H_ + t] + wf[2 * H_ + t];  // x3 = 3 identical copies
    s_b1[t] = b1v[f * H_ + t];
  }
  for (int i = t; i < H_ * K_; i += 256) s_w2[i] = w2[f * H_ * K_ + i];
  if (t < K_) { s_b2[t] = b2v[f * K_ + t]; s_tau[t] = tauv[f * K_ + t]; }
  __syncthreads();

  float x = stat[(size_t)b * F_ + f];
  x = (x >= 0.f) ? x : 0.f;              // NaN fails x>=0 -> 0; negatives -> 0
  float s[K_] = {0.f, 0.f, 0.f, 0.f, 0.f, 0.f, 0.f, 0.f};
  #pragma unroll
  for (int i = 0; i < H_; ++i) {
    float h = fmaf(x, s_w1s[i], s_b1[i]);
    h = (h >= 0.f) ? h : LEAKY * h;
    #pragma unroll
    for (int k = 0; k < K_; ++k) s[k] = fmaf(h, s_w2[i * K_ + k], s[k]);
  }
  float m = -1e30f;
  #pragma unroll
  for (int k = 0; k < K_; ++k) {
    float v = s[k] + s_b2[k];
    v = (v >= 0.f) ? v : LEAKY * v;
    v *= s_tau[k];
    s[k] = v;
    m = fmaxf(m, v);
  }
  float sum = 0.f;
  #pragma unroll
  for (int k = 0; k < K_; ++k) { s[k] = __expf(s[k] - m); sum += s[k]; }
  float inv = 1.f / sum;
  u16x8 hv;
  #pragma unroll
  for (int k = 0; k < K_; ++k) hv[k] = f2bf(s[k] * inv);
  *(u16x8*)(P + (size_t)b * PK + f * K_) = hv;       // 16B aligned store
}

// ---------------------------------------------------------------------------
// Wn rows (N-major!): Wn[o][j] = proj_w[o][j] for j<896 (straight bf16 copy)
__global__ __launch_bounds__(256) void wn_top_kernel(
    const float* __restrict__ pw, u16* __restrict__ Wn) {
  int idx = blockIdx.x * 256 + threadIdx.x;   // OUT_*896 total
  if (idx >= OUT_ * 896) return;
  int o = idx / 896, j = idx % 896;           // coalesced read & write along j
  Wn[(size_t)o * ZK + j] = f2bf(pw[(size_t)o * PROJ_IN + j]);
}

// Wn[o][896 + f*8 + k] = G[f,k,o] = sum_d emb[f,k,d] * proj_w[o, 896+f*128+d]
// One block per feature f; thread o owns output row o. pw read once (68 MB).
__global__ __launch_bounds__(256) void wn_g_kernel(
    const float* __restrict__ pw, const float* __restrict__ emb,
    u16* __restrict__ Wn) {
  const int f = blockIdx.x;
  const int o = threadIdx.x;
  __shared__ float s_emb[K_ * D_];            // 4 KB
  for (int i = threadIdx.x; i < K_ * D_; i += 256) s_emb[i] = emb[(size_t)f * K_ * D_ + i];
  __syncthreads();
  const float4* wrow = (const float4*)(pw + (size_t)o * PROJ_IN + 896 + f * D_);
  float g[K_] = {0.f, 0.f, 0.f, 0.f, 0.f, 0.f, 0.f, 0.f};
  #pragma unroll 4
  for (int d4 = 0; d4 < D_ / 4; ++d4) {
    float4 w = wrow[d4];
    int d = d4 * 4;
    #pragma unroll
    for (int k = 0; k < K_; ++k) {
      g[k] = fmaf(w.x, s_emb[k * D_ + d],     g[k]);
      g[k] = fmaf(w.y, s_emb[k * D_ + d + 1], g[k]);
      g[k] = fmaf(w.z, s_emb[k * D_ + d + 2], g[k]);
      g[k] = fmaf(w.w, s_emb[k * D_ + d + 3], g[k]);
    }
  }
  u16x8 hv;
  #pragma unroll
  for (int k = 0; k < K_; ++k) hv[k] = f2bf(g[k]);
  *(u16x8*)(Wn + (size_t)o * ZK + 896 + f * K_) = hv;  // 16B aligned
}

// ---------------------------------------------------------------------------
// MFMA GEMM: out[b][o] = relu( sum_k A[b][k] * Wn[o][k] + pb[o] )
// A segments: k<128 asr(f32), 128..895 mm(f32), 896.. P(bf16).
// BM=64 BN=32 BK=128; 256 thr = 4 waves, wave w owns rows w*16..w*16+15.
#define SAS 136   // LDS row stride (ushorts): 128 + 8 pad, keeps 16B align
__global__ __launch_bounds__(256) void gemm_kernel(
    const float* __restrict__ asr, const float* __restrict__ mm,
    const u16* __restrict__ P, const u16* __restrict__ Wn,
    const float* __restrict__ pb, float* __restrict__ out) {
  const int bm0 = blockIdx.x * 64;
  const int bn0 = blockIdx.y * 32;
  __shared__ u16 sA[64 * SAS];     // 17408 B
  __shared__ u16 sB[32 * SAS];     //  8704 B
  const int t = threadIdx.x;
  const int w = t >> 6, L = t & 63;
  const int l16 = L & 15, q8 = (L >> 4) * 8;
  f32x4 acc0 = {0.f, 0.f, 0.f, 0.f};
  f32x4 acc1 = {0.f, 0.f, 0.f, 0.f};

  // staging coords
  const int ar = t >> 2, akb = (t & 3) * 32;   // A: 4 thr/row, 32 k each
  const int bn = t >> 3, bkb = (t & 7) * 16;   // B: 8 thr/row, 16 k each

  for (int it = 0; it < ZK / 128; ++it) {      // 39 iters
    const int k0 = it * 128;
    // ---- stage A tile [64][128] ----
    if (k0 < 896) {
      const float* src;
      int c0;
      if (k0 < 128) { src = asr + (size_t)(bm0 + ar) * ASR_; c0 = k0 + akb; }
      else          { src = mm  + (size_t)(bm0 + ar) * MM_;  c0 = k0 - 128 + akb; }
      #pragma unroll
      for (int j = 0; j < 8; ++j) {
        float4 v = *(const float4*)(src + c0 + j * 4);
        u16x4 h = {f2bf(v.x), f2bf(v.y), f2bf(v.z), f2bf(v.w)};
        *(u16x4*)&sA[ar * SAS + akb + j * 4] = h;
      }
    } else {
      const u16* src = P + (size_t)(bm0 + ar) * PK + (k0 - 896) + akb;
      #pragma unroll
      for (int j = 0; j < 4; ++j)
        *(u16x8*)&sA[ar * SAS + akb + j * 8] = *(const u16x8*)(src + j * 8);
    }
    // ---- stage B tile [32][128] ----
    {
      const u16* src = Wn + (size_t)(bn0 + bn) * ZK + k0 + bkb;
      *(u16x8*)&sB[bn * SAS + bkb]     = *(const u16x8*)(src);
      *(u16x8*)&sB[bn * SAS + bkb + 8] = *(const u16x8*)(src + 8);
    }
    __syncthreads();
    // ---- MFMA: 4 k-steps of 32 ----
    #pragma unroll
    for (int ks = 0; ks < 4; ++ks) {
      s16x8 a  = *(const s16x8*)&sA[(w * 16 + l16) * SAS + ks * 32 + q8];
      s16x8 b0 = *(const s16x8*)&sB[l16 * SAS + ks * 32 + q8];
      s16x8 b1 = *(const s16x8*)&sB[(16 + l16) * SAS + ks * 32 + q8];
      acc0 = __builtin_amdgcn_mfma_f32_16x16x32_bf16(a, b0, acc0, 0, 0, 0);
      acc1 = __builtin_amdgcn_mfma_f32_16x16x32_bf16(a, b1, acc1, 0, 0, 0);
    }
    __syncthreads();
  }
  // ---- epilogue: bias + relu, C/D layout col=lane&15 row=quad*4+i ----
  const int n0 = bn0 + l16;
  const float bias0 = pb[n0], bias1 = pb[n0 + 16];
  const int mbase = bm0 + w * 16 + (q8 >> 3) * 4;   // (L>>4)*4
  #pragma unroll
  for (int i = 0; i < 4; ++i) {
    float v0 = acc0[i] + bias0;
    float v1 = acc1[i] + bias1;
    out[(size_t)(mbase + i) * OUT_ + n0]      = v0 > 0.f ? v0 : 0.f;
    out[(size_t)(mbase + i) * OUT_ + n0 + 16] = v1 > 0.f ? v1 : 0.f;
  }
}

// ---------------------------------------------------------------------------
extern "C" void kernel_launch(void* const* d_in, const int* in_sizes, int n_in,
                              void* d_out, int out_size, void* d_ws, size_t ws_size,
                              hipStream_t stream) {
  (void)in_sizes; (void)n_in; (void)out_size; (void)ws_size;
  const float* stat = (const float*)d_in[0];
  const float* asr  = (const float*)d_in[1];
  const float* mm   = (const float*)d_in[2];
  const float* w1   = (const float*)d_in[3];
  const float* b1   = (const float*)d_in[4];
  const float* w2   = (const float*)d_in[5];
  const float* b2   = (const float*)d_in[6];
  const float* tau  = (const float*)d_in[7];
  const float* emb  = (const float*)d_in[8];
  const float* pw   = (const float*)d_in[9];
  const float* pb   = (const float*)d_in[10];
  float* out = (float*)d_out;
  char* ws = (char*)d_ws;
  u16* P  = (u16*)(ws);                 // 16,777,216 B
  u16* Wn = (u16*)(ws + 16777216);      //  2,555,904 B  (total 19.33 MB)

  probs_kernel<<<dim3(F_, B_ / 256), 256, 0, stream>>>(stat, w1, b1, w2, b2, tau, P);
  wn_top_kernel<<<(OUT_ * 896 + 255) / 256, 256, 0, stream>>>(pw, Wn);
  wn_g_kernel<<<F_, 256, 0, stream>>>(pw, emb, Wn);
  gemm_kernel<<<dim3(B_ / 64, OUT_ / 32), 256, 0, stream>>>(asr, mm, P, Wn, pb, out);
}

// Round 3
// 180.347 us; speedup vs baseline: 1.1544x; 1.1544x over previous
//
#include <hip/hip_runtime.h>
#include <hip/hip_bf16.h>
#include <math.h>

#define LEAKY 0.01f
#define B_    2048
#define F_    512
#define H_    64
#define K_    8
#define D_    128
#define ASR_  128
#define MM_   768
#define OUT_  256
#define PROJ_IN 66432          // 128+768+512*128
#define ZK    4992             // 896 + 512*8 (emb folded into proj_w)
#define PK    4096             // F_*K_

// ---------------- workspace layout (bytes) ----------------
// P  : [B_][PK]   bf16  @ 0            16,777,216
// Wn : [OUT_][ZK] bf16  @ 16,777,216    2,555,904
// total 19,333,120  (proven safe in round 2; do NOT grow without evidence)

typedef unsigned short u16;
typedef u16   u16x4 __attribute__((ext_vector_type(4)));
typedef u16   u16x8 __attribute__((ext_vector_type(8)));
typedef short s16x8 __attribute__((ext_vector_type(8)));
typedef float f32x4 __attribute__((ext_vector_type(4)));

__device__ __forceinline__ u16 f2bf(float x) {   // RNE float->bf16 bits
  unsigned int u = __float_as_uint(x);
  u += 0x7fffu + ((u >> 16) & 1u);
  return (u16)(u >> 16);
}

// ---------------------------------------------------------------------------
// probs: block = 8 features x 256 batch rows. stat staged coalesced in LDS;
// inner loop register-blocked (8 rows x 8 k accumulators per thread).
#define W1S 65    // LDS stride for w1s/b1: banks (65f+i)%32 = (f+i)%32, distinct
#define W2S 516   // LDS stride for w2: 16B-aligned float4, banks 4f distinct
__global__ __launch_bounds__(256) void probs_kernel(
    const float* __restrict__ stat, const float* __restrict__ w1,
    const float* __restrict__ b1v, const float* __restrict__ w2,
    const float* __restrict__ b2v, const float* __restrict__ tauv,
    u16* __restrict__ P) {
  const int f0 = blockIdx.x * 8;
  const int b0 = blockIdx.y * 256;
  __shared__ float s_w1s[8 * W1S], s_b1[8 * W1S];
  __shared__ float s_w2[8 * W2S];
  __shared__ float s_b2[64], s_tau[64];
  __shared__ float s_x[256 * 8];
  const int t = threadIdx.x;
  for (int i = t; i < 8 * 64; i += 256) {
    int fl = i >> 6, h = i & 63;
    const float* wf = w1 + (size_t)(f0 + fl) * 192;
    s_w1s[fl * W1S + h] = wf[h] + wf[64 + h] + wf[128 + h];  // 3 identical copies of x
    s_b1[fl * W1S + h] = b1v[(size_t)(f0 + fl) * 64 + h];
  }
  for (int i = t; i < 8 * 512; i += 256) {
    int fl = i >> 9, idx = i & 511;
    s_w2[fl * W2S + idx] = w2[(size_t)(f0 + fl) * 512 + idx];
  }
  if (t < 64) {
    int fl = t >> 3, k = t & 7;
    s_b2[t]  = b2v[(f0 + fl) * 8 + k];
    s_tau[t] = tauv[(f0 + fl) * 8 + k];
  }
  for (int i = t; i < 2048; i += 256) {          // coalesced stat tile load
    int r = i >> 3, j = i & 7;
    float v = stat[(size_t)(b0 + r) * F_ + f0 + j];
    s_x[i] = (v >= 0.f) ? v : 0.f;               // NaN -> 0, neg -> 0
  }
  __syncthreads();

  const int fl = t & 7, rb = t >> 3;             // thread: feature fl, rows rb+32p
  float x[8];
  #pragma unroll
  for (int p = 0; p < 8; ++p) x[p] = s_x[(rb + 32 * p) * 8 + fl];
  float acc[8][8] = {{0.f}};
  const float* w1p = s_w1s + fl * W1S;
  const float* b1p = s_b1 + fl * W1S;
  const float* w2p = s_w2 + fl * W2S;
  #pragma unroll 8
  for (int i = 0; i < 64; ++i) {
    float wv = w1p[i], bv = b1p[i];
    float4 wa = *(const float4*)(w2p + i * 8);
    float4 wb = *(const float4*)(w2p + i * 8 + 4);
    #pragma unroll
    for (int p = 0; p < 8; ++p) {
      float h = fmaf(x[p], wv, bv);
      h = (h >= 0.f) ? h : LEAKY * h;
      acc[p][0] = fmaf(h, wa.x, acc[p][0]);
      acc[p][1] = fmaf(h, wa.y, acc[p][1]);
      acc[p][2] = fmaf(h, wa.z, acc[p][2]);
      acc[p][3] = fmaf(h, wa.w, acc[p][3]);
      acc[p][4] = fmaf(h, wb.x, acc[p][4]);
      acc[p][5] = fmaf(h, wb.y, acc[p][5]);
      acc[p][6] = fmaf(h, wb.z, acc[p][6]);
      acc[p][7] = fmaf(h, wb.w, acc[p][7]);
    }
  }
  #pragma unroll
  for (int p = 0; p < 8; ++p) {
    float s[K_];
    float m = -1e30f;
    #pragma unroll
    for (int k = 0; k < K_; ++k) {
      float v = acc[p][k] + s_b2[fl * 8 + k];
      v = (v >= 0.f) ? v : LEAKY * v;
      v *= s_tau[fl * 8 + k];
      s[k] = v;
      m = fmaxf(m, v);
    }
    float sum = 0.f;
    #pragma unroll
    for (int k = 0; k < K_; ++k) { s[k] = __expf(s[k] - m); sum += s[k]; }
    float inv = 1.f / sum;
    u16x8 hv;
    #pragma unroll
    for (int k = 0; k < K_; ++k) hv[k] = f2bf(s[k] * inv);
    *(u16x8*)(P + (size_t)(b0 + rb + 32 * p) * PK + (f0 + fl) * 8) = hv;
  }
}

// ---------------------------------------------------------------------------
// Wn rows (N-major): Wn[o][j] = proj_w[o][j] for j<896
__global__ __launch_bounds__(256) void wn_top_kernel(
    const float* __restrict__ pw, u16* __restrict__ Wn) {
  int idx = blockIdx.x * 256 + threadIdx.x;
  if (idx >= OUT_ * 896) return;
  int o = idx / 896, j = idx % 896;
  Wn[(size_t)o * ZK + j] = f2bf(pw[(size_t)o * PROJ_IN + j]);
}

// Wn[o][896+f*8+k] = sum_d emb[f,k,d] * pw[o, 896+f*128+d]
// Block (f, o-chunk of 64). 4 lanes per o-row, 64B contiguous per quad
// (fully coalesced); quad shfl_xor reduce.
__global__ __launch_bounds__(256) void wn_g_kernel(
    const float* __restrict__ pw, const float* __restrict__ emb,
    u16* __restrict__ Wn) {
  const int f = blockIdx.x;
  const int o0 = blockIdx.y * 64;
  __shared__ float s_emb[K_ * D_];               // 4 KB
  const int t = threadIdx.x;
  for (int i = t; i < K_ * D_; i += 256) s_emb[i] = emb[(size_t)f * K_ * D_ + i];
  __syncthreads();
  const int orow = t >> 2, dc = t & 3;
  const float* src = pw + (size_t)(o0 + orow) * PROJ_IN + 896 + f * D_;
  float g[K_] = {0.f, 0.f, 0.f, 0.f, 0.f, 0.f, 0.f, 0.f};
  #pragma unroll
  for (int j = 0; j < 8; ++j) {
    const int d = dc * 4 + j * 16;
    float4 w = *(const float4*)(src + d);
    #pragma unroll
    for (int k = 0; k < K_; ++k) {
      float4 e = *(const float4*)(s_emb + k * D_ + d);
      g[k] = fmaf(w.x, e.x, g[k]);
      g[k] = fmaf(w.y, e.y, g[k]);
      g[k] = fmaf(w.z, e.z, g[k]);
      g[k] = fmaf(w.w, e.w, g[k]);
    }
  }
  #pragma unroll
  for (int k = 0; k < K_; ++k) {
    g[k] += __shfl_xor(g[k], 1);
    g[k] += __shfl_xor(g[k], 2);
  }
  if (dc == 0) {
    u16x8 hv;
    #pragma unroll
    for (int k = 0; k < K_; ++k) hv[k] = f2bf(g[k]);
    *(u16x8*)(Wn + (size_t)(o0 + orow) * ZK + 896 + f * K_) = hv;
  }
}

// ---------------------------------------------------------------------------
// MFMA GEMM: out[b][o] = relu(sum_k A[b][k]*Wn[o][k] + bias[o])
// BM=32 BN=32 BK=128, 512 blocks (2/CU), register-prefetch double buffer.
#define SAS 136   // u16 row stride: 272 B = 17*16 (keeps b128 align)
__global__ __launch_bounds__(256) void gemm_kernel(
    const float* __restrict__ asr, const float* __restrict__ mm,
    const u16* __restrict__ P, const u16* __restrict__ Wn,
    const float* __restrict__ bias, float* __restrict__ out) {
  const int bm0 = blockIdx.x * 32;
  const int bn0 = blockIdx.y * 32;
  __shared__ u16 sA[32 * SAS];    // 8704 B
  __shared__ u16 sB[32 * SAS];    // 8704 B
  const int t = threadIdx.x;
  const int w = t >> 6, L = t & 63;
  const int l16 = L & 15, q8 = (L >> 4) * 8;
  const int mrow = (w >> 1) * 16, ncol = (w & 1) * 16;
  const int row = t >> 3, lk = t & 7;            // staging: 8 thr/row
  f32x4 acc = {0.f, 0.f, 0.f, 0.f};

  float4 fa[4];       // prefetch regs, fp32 A iters (it<7)
  u16x8 pa[2];        // prefetch regs, P iters
  u16x8 wb[2];        // prefetch regs, B

#define LOAD_TILES(IT)                                                        \
  {                                                                           \
    const int k0_ = (IT) * 128;                                               \
    if ((IT) == 0) {                                                          \
      const float* s_ = asr + (size_t)(bm0 + row) * ASR_ + lk * 4;            \
      fa[0] = *(const float4*)(s_);                                           \
      fa[1] = *(const float4*)(s_ + 32);                                      \
      fa[2] = *(const float4*)(s_ + 64);                                      \
      fa[3] = *(const float4*)(s_ + 96);                                      \
    } else if ((IT) < 7) {                                                    \
      const float* s_ = mm + (size_t)(bm0 + row) * MM_ + (k0_ - 128) + lk * 4;\
      fa[0] = *(const float4*)(s_);                                           \
      fa[1] = *(const float4*)(s_ + 32);                                      \
      fa[2] = *(const float4*)(s_ + 64);                                      \
      fa[3] = *(const float4*)(s_ + 96);                                      \
    } else {                                                                  \
      const u16* s_ = P + (size_t)(bm0 + row) * PK + (k0_ - 896) + lk * 8;    \
      pa[0] = *(const u16x8*)(s_);                                            \
      pa[1] = *(const u16x8*)(s_ + 64);                                       \
    }                                                                         \
    const u16* sb_ = Wn + (size_t)(bn0 + row) * ZK + k0_ + lk * 8;            \
    wb[0] = *(const u16x8*)(sb_);                                             \
    wb[1] = *(const u16x8*)(sb_ + 64);                                        \
  }

#define STORE_TILES(IT)                                                       \
  {                                                                           \
    if ((IT) < 7) {                                                           \
      _Pragma("unroll")                                                       \
      for (int j_ = 0; j_ < 4; ++j_) {                                        \
        u16x4 h_ = {f2bf(fa[j_].x), f2bf(fa[j_].y), f2bf(fa[j_].z),           \
                    f2bf(fa[j_].w)};                                          \
        *(u16x4*)&sA[row * SAS + lk * 4 + j_ * 32] = h_;                      \
      }                                                                       \
    } else {                                                                  \
      *(u16x8*)&sA[row * SAS + lk * 8] = pa[0];                               \
      *(u16x8*)&sA[row * SAS + lk * 8 + 64] = pa[1];                          \
    }                                                                         \
    *(u16x8*)&sB[row * SAS + lk * 8] = wb[0];                                 \
    *(u16x8*)&sB[row * SAS + lk * 8 + 64] = wb[1];                            \
  }

  LOAD_TILES(0);
  for (int it = 0; it < 39; ++it) {
    __syncthreads();               // previous iter's MFMA LDS reads complete
    STORE_TILES(it);
    __syncthreads();
    if (it < 38) LOAD_TILES(it + 1);   // overlap next global load with MFMA
    #pragma unroll
    for (int ks = 0; ks < 4; ++ks) {
      s16x8 a = *(const s16x8*)&sA[(mrow + l16) * SAS + ks * 32 + q8];
      s16x8 b = *(const s16x8*)&sB[(ncol + l16) * SAS + ks * 32 + q8];
      acc = __builtin_amdgcn_mfma_f32_16x16x32_bf16(a, b, acc, 0, 0, 0);
    }
  }
#undef LOAD_TILES
#undef STORE_TILES

  const int col = bn0 + ncol + l16;
  const float bv = bias[col];
  const int r0 = bm0 + mrow + (L >> 4) * 4;      // C/D: col=lane&15, row=quad*4+i
  #pragma unroll
  for (int i = 0; i < 4; ++i) {
    float v = acc[i] + bv;
    out[(size_t)(r0 + i) * OUT_ + col] = v > 0.f ? v : 0.f;
  }
}

// ---------------------------------------------------------------------------
extern "C" void kernel_launch(void* const* d_in, const int* in_sizes, int n_in,
                              void* d_out, int out_size, void* d_ws, size_t ws_size,
                              hipStream_t stream) {
  (void)in_sizes; (void)n_in; (void)out_size; (void)ws_size;
  const float* stat = (const float*)d_in[0];
  const float* asr  = (const float*)d_in[1];
  const float* mm   = (const float*)d_in[2];
  const float* w1   = (const float*)d_in[3];
  const float* b1   = (const float*)d_in[4];
  const float* w2   = (const float*)d_in[5];
  const float* b2   = (const float*)d_in[6];
  const float* tau  = (const float*)d_in[7];
  const float* emb  = (const float*)d_in[8];
  const float* pw   = (const float*)d_in[9];
  const float* pb   = (const float*)d_in[10];
  float* out = (float*)d_out;
  char* ws = (char*)d_ws;
  u16* P  = (u16*)(ws);                 // 16,777,216 B
  u16* Wn = (u16*)(ws + 16777216);      //  2,555,904 B

  probs_kernel<<<dim3(F_ / 8, B_ / 256), 256, 0, stream>>>(stat, w1, b1, w2, b2, tau, P);
  wn_top_kernel<<<(OUT_ * 896 + 255) / 256, 256, 0, stream>>>(pw, Wn);
  wn_g_kernel<<<dim3(F_, 4), 256, 0, stream>>>(pw, emb, Wn);
  gemm_kernel<<<dim3(B_ / 32, OUT_ / 32), 256, 0, stream>>>(asr, mm, P, Wn, pb, out);
}

// Round 4
// 167.064 us; speedup vs baseline: 1.2462x; 1.0795x over previous
//
#include <hip/hip_runtime.h>
#include <hip/hip_bf16.h>
#include <math.h>

#define LEAKY 0.01f
#define B_    2048
#define F_    512
#define H_    64
#define K_    8
#define D_    128
#define ASR_  128
#define MM_   768
#define OUT_  256
#define PROJ_IN 66432          // 128+768+512*128
#define ZK    4992             // 896 + 512*8 (emb folded into proj_w)
#define PK    4096             // F_*K_
#define NSPLIT 4               // gemm split-K factor

// ---------------- workspace layout (bytes) ----------------
// P    : [B_][PK]   bf16        @ 0           16,777,216
// Wn   : [OUT_][ZK] bf16        @ 16,777,216   2,555,904
// part : [4][B_][OUT_] fp32     @ 19,333,120   8,388,608
// total 27,721,728  (ws_size measured ~272 MB via poison WRITE_SIZE; the
// harness re-poisons ALL of ws each iter -> ~42 us fixed cost regardless)

typedef unsigned short u16;
typedef u16   u16x4 __attribute__((ext_vector_type(4)));
typedef u16   u16x8 __attribute__((ext_vector_type(8)));
typedef short s16x8 __attribute__((ext_vector_type(8)));
typedef float f32x4 __attribute__((ext_vector_type(4)));

__device__ __forceinline__ u16 f2bf(float x) {   // RNE float->bf16 bits
  unsigned int u = __float_as_uint(x);
  u += 0x7fffu + ((u >> 16) & 1u);
  return (u16)(u >> 16);
}

// ---------------------------------------------------------------------------
// Fused producers. Heterogeneous blocks:
//   bid <  512        : probs tile  (8 features x 256 rows)
//   512 <= bid < 2560 : wn_g item   (feature f, 64 o-rows)
//   2560 <= bid < 2784: wn_top slab (1024 elements)
// HBM-bound wn_g blocks overlap with VALU-bound probs blocks across the CU.
#define W1S 65
#define W2S 516
#define PRODUCER_BLOCKS (512 + 2048 + 224)

__global__ __launch_bounds__(256) void producer_kernel(
    const float* __restrict__ stat, const float* __restrict__ w1,
    const float* __restrict__ b1v, const float* __restrict__ w2,
    const float* __restrict__ b2v, const float* __restrict__ tauv,
    const float* __restrict__ pw, const float* __restrict__ emb,
    u16* __restrict__ P, u16* __restrict__ Wn) {
  __shared__ __align__(16) char smem[29376];
  const int bid = blockIdx.x;
  const int t = threadIdx.x;

  if (bid < 512) {
    // ---------------- probs ----------------
    const int f0 = (bid & 63) * 8;
    const int b0 = (bid >> 6) * 256;
    float* s_w1s = (float*)(smem);                    // 8*65
    float* s_b1  = (float*)(smem + 2080);             // 8*65
    float* s_w2  = (float*)(smem + 4160);             // 8*516 (16B aligned)
    float* s_b2  = (float*)(smem + 20672);            // 64
    float* s_tau = (float*)(smem + 20928);            // 64
    float* s_x   = (float*)(smem + 21184);            // 256*8
    for (int i = t; i < 8 * 64; i += 256) {
      int fl = i >> 6, h = i & 63;
      const float* wf = w1 + (size_t)(f0 + fl) * 192;
      s_w1s[fl * W1S + h] = wf[h] + wf[64 + h] + wf[128 + h];
      s_b1[fl * W1S + h] = b1v[(size_t)(f0 + fl) * 64 + h];
    }
    for (int i = t; i < 8 * 512; i += 256) {
      int fl = i >> 9, idx = i & 511;
      s_w2[fl * W2S + idx] = w2[(size_t)(f0 + fl) * 512 + idx];
    }
    if (t < 64) {
      int fl = t >> 3, k = t & 7;
      s_b2[t]  = b2v[(f0 + fl) * 8 + k];
      s_tau[t] = tauv[(f0 + fl) * 8 + k];
    }
    for (int i = t; i < 2048; i += 256) {             // coalesced stat tile
      int r = i >> 3, j = i & 7;
      float v = stat[(size_t)(b0 + r) * F_ + f0 + j];
      s_x[i] = (v >= 0.f) ? v : 0.f;                  // NaN -> 0, neg -> 0
    }
    __syncthreads();

    const int fl = t & 7, rb = t >> 3;
    float x[8];
    #pragma unroll
    for (int p = 0; p < 8; ++p) x[p] = s_x[(rb + 32 * p) * 8 + fl];
    float acc[8][8] = {{0.f}};
    const float* w1p = s_w1s + fl * W1S;
    const float* b1p = s_b1 + fl * W1S;
    const float* w2p = s_w2 + fl * W2S;
    #pragma unroll 8
    for (int i = 0; i < 64; ++i) {
      float wv = w1p[i], bv = b1p[i];
      float4 wa = *(const float4*)(w2p + i * 8);
      float4 wb = *(const float4*)(w2p + i * 8 + 4);
      #pragma unroll
      for (int p = 0; p < 8; ++p) {
        float h = fmaf(x[p], wv, bv);
        h = (h >= 0.f) ? h : LEAKY * h;
        acc[p][0] = fmaf(h, wa.x, acc[p][0]);
        acc[p][1] = fmaf(h, wa.y, acc[p][1]);
        acc[p][2] = fmaf(h, wa.z, acc[p][2]);
        acc[p][3] = fmaf(h, wa.w, acc[p][3]);
        acc[p][4] = fmaf(h, wb.x, acc[p][4]);
        acc[p][5] = fmaf(h, wb.y, acc[p][5]);
        acc[p][6] = fmaf(h, wb.z, acc[p][6]);
        acc[p][7] = fmaf(h, wb.w, acc[p][7]);
      }
    }
    #pragma unroll
    for (int p = 0; p < 8; ++p) {
      float s[K_];
      float m = -1e30f;
      #pragma unroll
      for (int k = 0; k < K_; ++k) {
        float v = acc[p][k] + s_b2[fl * 8 + k];
        v = (v >= 0.f) ? v : LEAKY * v;
        v *= s_tau[fl * 8 + k];
        s[k] = v;
        m = fmaxf(m, v);
      }
      float sum = 0.f;
      #pragma unroll
      for (int k = 0; k < K_; ++k) { s[k] = __expf(s[k] - m); sum += s[k]; }
      float inv = 1.f / sum;
      u16x8 hv;
      #pragma unroll
      for (int k = 0; k < K_; ++k) hv[k] = f2bf(s[k] * inv);
      *(u16x8*)(P + (size_t)(b0 + rb + 32 * p) * PK + (f0 + fl) * 8) = hv;
    }
  } else if (bid < 2560) {
    // ---------------- wn_g: Wn[o][896+f*8+k] = sum_d emb[f,k,d]*pw[o,896+f*128+d]
    const int item = bid - 512;
    const int f = item >> 2;
    const int o0 = (item & 3) * 64;
    float* s_emb = (float*)smem;                      // 4 KB
    for (int i = t; i < K_ * D_; i += 256) s_emb[i] = emb[(size_t)f * K_ * D_ + i];
    __syncthreads();
    const int orow = t >> 2, dc = t & 3;              // quad reads 64B contiguous
    const float* src = pw + (size_t)(o0 + orow) * PROJ_IN + 896 + f * D_;
    float g[K_] = {0.f, 0.f, 0.f, 0.f, 0.f, 0.f, 0.f, 0.f};
    #pragma unroll
    for (int j = 0; j < 8; ++j) {
      const int d = dc * 4 + j * 16;
      float4 w = *(const float4*)(src + d);
      #pragma unroll
      for (int k = 0; k < K_; ++k) {
        float4 e = *(const float4*)(s_emb + k * D_ + d);
        g[k] = fmaf(w.x, e.x, g[k]);
        g[k] = fmaf(w.y, e.y, g[k]);
        g[k] = fmaf(w.z, e.z, g[k]);
        g[k] = fmaf(w.w, e.w, g[k]);
      }
    }
    #pragma unroll
    for (int k = 0; k < K_; ++k) {
      g[k] += __shfl_xor(g[k], 1);
      g[k] += __shfl_xor(g[k], 2);
    }
    if (dc == 0) {
      u16x8 hv;
      #pragma unroll
      for (int k = 0; k < K_; ++k) hv[k] = f2bf(g[k]);
      *(u16x8*)(Wn + (size_t)(o0 + orow) * ZK + 896 + f * K_) = hv;
    }
  } else {
    // ---------------- wn_top: Wn[o][j] = bf16(pw[o][j]), j<896
    const int item = bid - 2560;                      // 224 blocks x 1024 elems
    #pragma unroll
    for (int r = 0; r < 4; ++r) {
      int idx = item * 1024 + r * 256 + t;            // coalesced
      int o = idx / 896, j = idx % 896;
      Wn[(size_t)o * ZK + j] = f2bf(pw[(size_t)o * PROJ_IN + j]);
    }
  }
}

// ---------------------------------------------------------------------------
// MFMA GEMM, split-K=4: part[kz][b][o] = sum_{k in slice} A[b][k]*Wn[o][k]
// BM=32 BN=32 BK=128; grid (64,8,4) = 2048 blocks (~8/CU), reg prefetch.
#define SAS 136   // u16 row stride: 272 B = 17*16
__global__ __launch_bounds__(256) void gemm_kernel(
    const float* __restrict__ asr, const float* __restrict__ mm,
    const u16* __restrict__ P, const u16* __restrict__ Wn,
    float* __restrict__ part) {
  const int bm0 = blockIdx.x * 32;
  const int bn0 = blockIdx.y * 32;
  const int kz  = blockIdx.z;
  const int it0 = kz * 10;
  const int itn = (kz == 3) ? 9 : 10;                 // 10+10+10+9 = 39 iters
  __shared__ u16 sA[32 * SAS];
  __shared__ u16 sB[32 * SAS];
  const int t = threadIdx.x;
  const int w = t >> 6, L = t & 63;
  const int l16 = L & 15, q8 = (L >> 4) * 8;
  const int mrow = (w >> 1) * 16, ncol = (w & 1) * 16;
  const int row = t >> 3, lk = t & 7;
  f32x4 acc = {0.f, 0.f, 0.f, 0.f};

  float4 fa[4];
  u16x8 pa[2];
  u16x8 wb[2];

#define LOAD_TILES(IT)                                                        \
  {                                                                           \
    const int k0_ = (IT) * 128;                                               \
    if (k0_ == 0) {                                                           \
      const float* s_ = asr + (size_t)(bm0 + row) * ASR_ + lk * 4;            \
      fa[0] = *(const float4*)(s_);                                           \
      fa[1] = *(const float4*)(s_ + 32);                                      \
      fa[2] = *(const float4*)(s_ + 64);                                      \
      fa[3] = *(const float4*)(s_ + 96);                                      \
    } else if (k0_ < 896) {                                                   \
      const float* s_ = mm + (size_t)(bm0 + row) * MM_ + (k0_ - 128) + lk * 4;\
      fa[0] = *(const float4*)(s_);                                           \
      fa[1] = *(const float4*)(s_ + 32);                                      \
      fa[2] = *(const float4*)(s_ + 64);                                      \
      fa[3] = *(const float4*)(s_ + 96);                                      \
    } else {                                                                  \
      const u16* s_ = P + (size_t)(bm0 + row) * PK + (k0_ - 896) + lk * 8;    \
      pa[0] = *(const u16x8*)(s_);                                            \
      pa[1] = *(const u16x8*)(s_ + 64);                                       \
    }                                                                         \
    const u16* sb_ = Wn + (size_t)(bn0 + row) * ZK + k0_ + lk * 8;            \
    wb[0] = *(const u16x8*)(sb_);                                             \
    wb[1] = *(const u16x8*)(sb_ + 64);                                        \
  }

#define STORE_TILES(IT)                                                       \
  {                                                                           \
    if ((IT) * 128 < 896) {                                                   \
      _Pragma("unroll")                                                       \
      for (int j_ = 0; j_ < 4; ++j_) {                                        \
        u16x4 h_ = {f2bf(fa[j_].x), f2bf(fa[j_].y), f2bf(fa[j_].z),           \
                    f2bf(fa[j_].w)};                                          \
        *(u16x4*)&sA[row * SAS + lk * 4 + j_ * 32] = h_;                      \
      }                                                                       \
    } else {                                                                  \
      *(u16x8*)&sA[row * SAS + lk * 8] = pa[0];                               \
      *(u16x8*)&sA[row * SAS + lk * 8 + 64] = pa[1];                          \
    }                                                                         \
    *(u16x8*)&sB[row * SAS + lk * 8] = wb[0];                                 \
    *(u16x8*)&sB[row * SAS + lk * 8 + 64] = wb[1];                            \
  }

  LOAD_TILES(it0);
  for (int it = it0; it < it0 + itn; ++it) {
    __syncthreads();
    STORE_TILES(it);
    __syncthreads();
    if (it + 1 < it0 + itn) LOAD_TILES(it + 1);
    #pragma unroll
    for (int ks = 0; ks < 4; ++ks) {
      s16x8 a = *(const s16x8*)&sA[(mrow + l16) * SAS + ks * 32 + q8];
      s16x8 b = *(const s16x8*)&sB[(ncol + l16) * SAS + ks * 32 + q8];
      acc = __builtin_amdgcn_mfma_f32_16x16x32_bf16(a, b, acc, 0, 0, 0);
    }
  }
#undef LOAD_TILES
#undef STORE_TILES

  const int col = bn0 + ncol + l16;
  const int r0 = bm0 + mrow + (L >> 4) * 4;           // C/D: col=lane&15, row=quad*4+i
  float* dst = part + (size_t)kz * B_ * OUT_;
  #pragma unroll
  for (int i = 0; i < 4; ++i)
    dst[(size_t)(r0 + i) * OUT_ + col] = acc[i];
}

// ---------------------------------------------------------------------------
// combine: out = relu(sum_kz part[kz] + bias), float4 per thread
__global__ __launch_bounds__(256) void combine_kernel(
    const float* __restrict__ part, const float* __restrict__ pb,
    float* __restrict__ out) {
  const int idx4 = (blockIdx.x * 256 + threadIdx.x) * 4;   // grid 512 covers B_*OUT_
  const int o = idx4 & (OUT_ - 1);
  float4 a0 = *(const float4*)(part + idx4);
  float4 a1 = *(const float4*)(part + (size_t)B_ * OUT_ + idx4);
  float4 a2 = *(const float4*)(part + (size_t)2 * B_ * OUT_ + idx4);
  float4 a3 = *(const float4*)(part + (size_t)3 * B_ * OUT_ + idx4);
  float4 bv = *(const float4*)(pb + o);
  float4 r;
  r.x = a0.x + a1.x + a2.x + a3.x + bv.x;
  r.y = a0.y + a1.y + a2.y + a3.y + bv.y;
  r.z = a0.z + a1.z + a2.z + a3.z + bv.z;
  r.w = a0.w + a1.w + a2.w + a3.w + bv.w;
  r.x = r.x > 0.f ? r.x : 0.f;
  r.y = r.y > 0.f ? r.y : 0.f;
  r.z = r.z > 0.f ? r.z : 0.f;
  r.w = r.w > 0.f ? r.w : 0.f;
  *(float4*)(out + idx4) = r;
}

// ---------------------------------------------------------------------------
extern "C" void kernel_launch(void* const* d_in, const int* in_sizes, int n_in,
                              void* d_out, int out_size, void* d_ws, size_t ws_size,
                              hipStream_t stream) {
  (void)in_sizes; (void)n_in; (void)out_size; (void)ws_size;
  const float* stat = (const float*)d_in[0];
  const float* asr  = (const float*)d_in[1];
  const float* mm   = (const float*)d_in[2];
  const float* w1   = (const float*)d_in[3];
  const float* b1   = (const float*)d_in[4];
  const float* w2   = (const float*)d_in[5];
  const float* b2   = (const float*)d_in[6];
  const float* tau  = (const float*)d_in[7];
  const float* emb  = (const float*)d_in[8];
  const float* pw   = (const float*)d_in[9];
  const float* pb   = (const float*)d_in[10];
  float* out = (float*)d_out;
  char* ws = (char*)d_ws;
  u16*   P    = (u16*)(ws);                 // 16,777,216 B
  u16*   Wn   = (u16*)(ws + 16777216);      //  2,555,904 B
  float* part = (float*)(ws + 19333120);    //  8,388,608 B

  producer_kernel<<<PRODUCER_BLOCKS, 256, 0, stream>>>(
      stat, w1, b1, w2, b2, tau, pw, emb, P, Wn);
  gemm_kernel<<<dim3(B_ / 32, OUT_ / 32, NSPLIT), 256, 0, stream>>>(
      asr, mm, P, Wn, part);
  combine_kernel<<<B_ * OUT_ / 1024, 256, 0, stream>>>(part, pb, out);
}